// Round 7
// baseline (17.098 us; speedup 1.0000x reference)
//
#include <hip/hip_runtime.h>
#include <math.h>

namespace {

constexpr int BATCH = 16;
constexpr int Ww = 96;
constexpr int NP = 96 * 96;      // 9216
constexpr int NHYP = 128;
constexpr int HPB = 4;           // hypotheses per block
constexpr int GPB = NHYP / HPB;  // 32 blocks per batch

__device__ inline void waveSum2D(double& a, double& b) {
#pragma unroll
  for (int o = 32; o >= 1; o >>= 1) {
    a += __shfl_xor(a, o, 64);
    b += __shfl_xor(b, o, 64);
  }
}
__device__ inline double waveSumD(double v) {
#pragma unroll
  for (int o = 32; o >= 1; o >>= 1) v += __shfl_xor(v, o, 64);
  return v;
}

// Kernel 1: 512 blocks x 256 threads; block owns (batch b, 4 hyps).
// Phase 1 (redundant per block, bitwise-identical across a batch's blocks):
//   f64 2x2 solve per hyp + batch stats (ddof=1, two-pass) + one-sided z>2
//   outlier replacement, in LDS/registers — no global hyp tables.
// Phase 2: votes. Thread-owns-pixels, so each hypothesis's 64 tests per wave
//   collapse to __popcll(__ballot(pred)): VALU is mul+fma+cmp only, count
//   accumulates on the scalar pipe, no shuffle reduction needed.
//   Vote test yy*u + yx*v > y*u + x*v (reference's normalization is
//   sign-preserving; NaN compares false either way).
// Tail: t==0 folds the block's 4 hyps into 3 f64 partials {w, py*w, px*w},
//   plain store to the block's OWN slot. No atomics/fences/tickets (R2/R3/R5:
//   every in-kernel completion scheme loses 9-30 µs to L2 coherence traffic).
__global__ __launch_bounds__(256, 4)
void vote_kernel(const float* __restrict__ uv, const int* __restrict__ pair,
                 double* __restrict__ partials /* [BATCH][3][GPB] */) {
  __shared__ double sPy[NHYP], sPx[NHYP];
  __shared__ float sWm[NHYP];
  __shared__ int sNan[NHYP];
  __shared__ double sh1[2][2], sh2[2][2];
  __shared__ unsigned sC[4][HPB];

  const int t = threadIdx.x;
  const int lane = t & 63;
  const int wv = t >> 6;
  const int b = blockIdx.x >> 5;         // / GPB
  const int g = blockIdx.x & (GPB - 1);
  const float* uvb = uv + (size_t)b * 2 * NP;

  // ---- prefetch first 3 pixel-load pairs (independent of phase 1) ----
  float4 pu[3], pv[3];
#pragma unroll
  for (int i = 0; i < 3; ++i) {
    const int p = (i * 256 + t) * 4;
    pu[i] = *(const float4*)(uvb + p);
    pv[i] = *(const float4*)(uvb + NP + p);
  }

  // ---- phase 1: solves (threads 0..127) ----
  double Yy = 0.0, Yx = 0.0;
  if (t < NHYP) {
    int i0 = pair[(b * NHYP + t) * 2 + 0];
    int i1 = pair[(b * NHYP + t) * 2 + 1];
    double u0 = uvb[i0], v0 = uvb[NP + i0];
    double u1 = uvb[i1], v1 = uvb[NP + i1];
    double y0 = (double)(i0 / Ww), x0 = (double)(i0 % Ww);
    double y1 = (double)(i1 / Ww), x1 = (double)(i1 % Ww);
    // A = [[u0,-u1],[v0,-v1]], Bvec = [y1-y0, x1-x0]; s = (A^-1 Bvec).x
    double det = u1 * v0 - u0 * v1;
    double s = (u1 * (x1 - x0) - v1 * (y1 - y0)) / det;
    Yy = s * u0 + y0;
    Yx = s * v0 + x0;
  }
  double sy = Yy, sx = Yx;
  waveSum2D(sy, sx);                     // waves 2,3 shuffle zeros: harmless
  if (lane == 0 && wv < 2) { sh1[wv][0] = sy; sh1[wv][1] = sx; }
  __syncthreads();
  const double my = (sh1[0][0] + sh1[1][0]) * (1.0 / NHYP);
  const double mx = (sh1[0][1] + sh1[1][1]) * (1.0 / NHYP);
  const double dy = Yy - my, dx = Yx - mx;
  double qy = dy * dy, qx = dx * dx;
  waveSum2D(qy, qx);
  if (lane == 0 && wv < 2) { sh2[wv][0] = qy; sh2[wv][1] = qx; }
  __syncthreads();
  if (t < NHYP) {
    double vy = (sh2[0][0] + sh2[1][0]) * (1.0 / (NHYP - 1));
    double vx = (sh2[0][1] + sh2[1][1]) * (1.0 / (NHYP - 1));
    // dy/sqrt(vy) > 2  <=>  dy > 2*sqrt(vy)  (incl. 0/0->NaN->false, +inf)
    bool outl = (dy > 2.0 * sqrt(vy)) || (dx > 2.0 * sqrt(vx));
    double py = outl ? my : Yy;
    double px = outl ? mx : Yx;
    sPy[t] = py;
    sPx[t] = px;
    // h_in_mask==1 <=> trunc(Yp) hits a lattice point <=> Yp in (-1,96)^2
    sWm[t] = (py > -1.0 && py < 96.0 && px > -1.0 && px < 96.0) ? 10.0f : 1.0f;
    sNan[t] = (isnan(py) || isnan(px)) ? 1 : 0;
  }
  __syncthreads();

  // ---- phase 2: votes for the block's 4 hyps ----
  const int hb = g * HPB;
  float yy[HPB], yx[HPB];
#pragma unroll
  for (int h = 0; h < HPB; ++h) {
    yy[h] = (float)sPy[hb + h];
    yx[h] = (float)sPx[hb + h];
  }
  unsigned c[HPB] = {0, 0, 0, 0};        // wave-uniform (ballot counts)
#pragma unroll
  for (int it = 0; it < 9; ++it) {
    float4 u4, v4;
    if (it < 3) {
      u4 = pu[it]; v4 = pv[it];
    } else {
      const int p = (it * 256 + t) * 4;  // 96%4==0: group stays in one row
      u4 = *(const float4*)(uvb + p);
      v4 = *(const float4*)(uvb + NP + p);
    }
    const int p = (it * 256 + t) * 4;
    const int yi = p / Ww;
    const float fy = (float)yi;
    const float fx = (float)(p - yi * Ww);
    const float k0 = fy * u4.x + fx * v4.x;
    const float k1 = fy * u4.y + (fx + 1.0f) * v4.y;
    const float k2 = fy * u4.z + (fx + 2.0f) * v4.z;
    const float k3 = fy * u4.w + (fx + 3.0f) * v4.w;
#pragma unroll
    for (int h = 0; h < HPB; ++h) {
      c[h] += __popcll(__ballot(fmaf(yy[h], u4.x, yx[h] * v4.x) > k0));
      c[h] += __popcll(__ballot(fmaf(yy[h], u4.y, yx[h] * v4.y) > k1));
      c[h] += __popcll(__ballot(fmaf(yy[h], u4.z, yx[h] * v4.z) > k2));
      c[h] += __popcll(__ballot(fmaf(yy[h], u4.w, yx[h] * v4.w) > k3));
    }
  }
  if (lane == 0) {
#pragma unroll
    for (int h = 0; h < HPB; ++h) sC[wv][h] = c[h];
  }
  __syncthreads();

  // ---- tail: fold 4 hyps -> 3 partials, plain store to own slot ----
  if (t == 0) {
    double wsum = 0.0, ny = 0.0, nx = 0.0;
#pragma unroll
    for (int h = 0; h < HPB; ++h) {
      const int hh = hb + h;
      unsigned cnt = sC[0][h] + sC[1][h] + sC[2][h] + sC[3][h];
      if (!sNan[hh]) {                   // guard: NaN*0 would poison the sum
        double w = (double)cnt * (double)sWm[hh];
        wsum += w;
        ny += sPy[hh] * w;
        nx += sPx[hh] * w;
      }
    }
    double* slot = partials + (size_t)b * 3 * GPB;
    slot[0 * GPB + g] = wsum;
    slot[1 * GPB + g] = ny;
    slot[2 * GPB + g] = nx;
  }
}

// Kernel 2: 16 blocks x 192 threads (3 waves: w, ny, nx). Deterministic
// fixed-order reduce of the 32 slots; divide once; write out[, ::-1].
__global__ __launch_bounds__(192)
void final_kernel(const double* __restrict__ partials,
                  float* __restrict__ out) {
  __shared__ double sD[3];
  const int t = threadIdx.x;
  const int lane = t & 63;
  const int wv = t >> 6;
  const int b = blockIdx.x;

  double val = (lane < GPB)
                   ? partials[((size_t)b * 3 + wv) * GPB + lane]
                   : 0.0;
  val = waveSumD(val);
  if (lane == 0) sD[wv] = val;
  __syncthreads();
  if (t == 0) {
    double wsum = sD[0];
    out[b * 2 + 0] = (float)(sD[2] / wsum);   // weighted_mean[:, ::-1]
    out[b * 2 + 1] = (float)(sD[1] / wsum);
  }
}

}  // namespace

extern "C" void kernel_launch(void* const* d_in, const int* in_sizes, int n_in,
                              void* d_out, int out_size, void* d_ws, size_t ws_size,
                              hipStream_t stream) {
  const float* uv = (const float*)d_in[0];   // (16,2,96,96) f32
  // d_in[1] = mask, unused (all ones; never read by the reference math)
  const int* pair = (const int*)d_in[2];     // (16,128,2) i32
  float* out = (float*)d_out;                // (16,2) f32

  double* partials = (double*)d_ws;          // 16*3*32*8 = 12288 B

  vote_kernel<<<BATCH * GPB, 256, 0, stream>>>(uv, pair, partials);
  final_kernel<<<BATCH, 192, 0, stream>>>(partials, out);
}

// Round 8
// 14.332 us; speedup vs baseline: 1.1930x; 1.1930x over previous
//
#include <hip/hip_runtime.h>
#include <math.h>

namespace {

constexpr int BATCH = 16;
constexpr int Ww = 96;
constexpr int NP = 96 * 96;      // 9216
constexpr int NHYP = 128;
constexpr int HPB = 4;           // hypotheses per block
constexpr int GPB = NHYP / HPB;  // 32 blocks per batch
constexpr int THREADS = 512;     // 8 waves: keeps 16 waves/CU at 2 blocks/CU

__device__ inline void waveSum2D(double& a, double& b) {
#pragma unroll
  for (int o = 32; o >= 1; o >>= 1) {
    a += __shfl_xor(a, o, 64);
    b += __shfl_xor(b, o, 64);
  }
}
__device__ inline void waveSum2I(int& a, int& b) {
#pragma unroll
  for (int o = 32; o >= 1; o >>= 1) {
    a += __shfl_xor(a, o, 64);
    b += __shfl_xor(b, o, 64);
  }
}
__device__ inline double waveSumD(double v) {
#pragma unroll
  for (int o = 32; o >= 1; o >>= 1) v += __shfl_xor(v, o, 64);
  return v;
}

// Kernel 1: 512 blocks x 512 threads; block owns (batch b, 4 hyps).
// Occupancy: 2 blocks/CU x 8 waves = 16 waves/CU = 4 waves/SIMD (same as the
// 15.09 µs R6 config — R7's regression was dropping this to 2 waves/SIMD).
// Phase 1 (threads 0..127; redundant per block, bitwise-identical across a
//   batch's blocks): f64 2x2 solve + batch stats (ddof=1) + one-sided z>2
//   outlier replacement — identical math to R6.
// Phase 2: votes for the block's 4 hyps; 18 px/thread = 4 float4-iters +
//   1 float2-iter (4|96 and 2|96: a vector group never crosses a row).
//   Vote test yy*u + yx*v > y*u + x*v (reference's normalization is
//   sign-preserving; NaN compares false either way).
// Tail: t==0 folds 4 hyps into 3 f64 partials {w, py*w, px*w}, plain store
//   to the block's OWN slot. No atomics/fences/tickets (R2/R3/R5: every
//   in-kernel completion scheme lost 9-30 µs to coherence traffic).
__global__ __launch_bounds__(THREADS, 4)
void vote_kernel(const float* __restrict__ uv, const int* __restrict__ pair,
                 double* __restrict__ partials /* [BATCH][3][GPB] */) {
  __shared__ double sPy[NHYP], sPx[NHYP];
  __shared__ float sWm[NHYP];
  __shared__ int sNan[NHYP];
  __shared__ double sh1[2][2], sh2[2][2];
  __shared__ int sC[8][HPB];

  const int t = threadIdx.x;
  const int lane = t & 63;
  const int wv = t >> 6;
  const int b = blockIdx.x >> 5;         // / GPB
  const int g = blockIdx.x & (GPB - 1);
  const float* uvb = uv + (size_t)b * 2 * NP;

  // ---- phase 1: solves (threads 0..127) ----
  double Yy = 0.0, Yx = 0.0;
  if (t < NHYP) {
    int i0 = pair[(b * NHYP + t) * 2 + 0];
    int i1 = pair[(b * NHYP + t) * 2 + 1];
    double u0 = uvb[i0], v0 = uvb[NP + i0];
    double u1 = uvb[i1], v1 = uvb[NP + i1];
    double y0 = (double)(i0 / Ww), x0 = (double)(i0 % Ww);
    double y1 = (double)(i1 / Ww), x1 = (double)(i1 % Ww);
    // A = [[u0,-u1],[v0,-v1]], Bvec = [y1-y0, x1-x0]; s = (A^-1 Bvec).x
    double det = u1 * v0 - u0 * v1;
    double s = (u1 * (x1 - x0) - v1 * (y1 - y0)) / det;
    Yy = s * u0 + y0;
    Yx = s * v0 + x0;
  }
  double sy = Yy, sx = Yx;
  waveSum2D(sy, sx);                     // waves 2..7 shuffle zeros: harmless
  if (lane == 0 && wv < 2) { sh1[wv][0] = sy; sh1[wv][1] = sx; }
  __syncthreads();
  const double my = (sh1[0][0] + sh1[1][0]) * (1.0 / NHYP);
  const double mx = (sh1[0][1] + sh1[1][1]) * (1.0 / NHYP);
  const double dy = Yy - my, dx = Yx - mx;
  double qy = dy * dy, qx = dx * dx;
  waveSum2D(qy, qx);
  if (lane == 0 && wv < 2) { sh2[wv][0] = qy; sh2[wv][1] = qx; }
  __syncthreads();
  if (t < NHYP) {
    double vy = (sh2[0][0] + sh2[1][0]) * (1.0 / (NHYP - 1));
    double vx = (sh2[0][1] + sh2[1][1]) * (1.0 / (NHYP - 1));
    // dy/sqrt(vy) > 2  <=>  dy > 2*sqrt(vy)  (incl. 0/0->NaN->false, +inf)
    bool outl = (dy > 2.0 * sqrt(vy)) || (dx > 2.0 * sqrt(vx));
    double py = outl ? my : Yy;
    double px = outl ? mx : Yx;
    sPy[t] = py;
    sPx[t] = px;
    // h_in_mask==1 <=> trunc(Yp) hits a lattice point <=> Yp in (-1,96)^2
    sWm[t] = (py > -1.0 && py < 96.0 && px > -1.0 && px < 96.0) ? 10.0f : 1.0f;
    sNan[t] = (isnan(py) || isnan(px)) ? 1 : 0;
  }
  __syncthreads();

  // ---- phase 2: votes for the block's 4 hyps ----
  const int hb = g * HPB;
  float yy[HPB], yx[HPB];
#pragma unroll
  for (int h = 0; h < HPB; ++h) {
    yy[h] = (float)sPy[hb + h];
    yx[h] = (float)sPx[hb + h];
  }
  int c[HPB] = {0, 0, 0, 0};
#pragma unroll
  for (int it = 0; it < 4; ++it) {
    const int p = (it * THREADS + t) * 4;
    const float4 u4 = *(const float4*)(uvb + p);
    const float4 v4 = *(const float4*)(uvb + NP + p);
    const int yi = p / Ww;
    const float fy = (float)yi;
    const float fx = (float)(p - yi * Ww);
    const float k0 = fy * u4.x + fx * v4.x;
    const float k1 = fy * u4.y + (fx + 1.0f) * v4.y;
    const float k2 = fy * u4.z + (fx + 2.0f) * v4.z;
    const float k3 = fy * u4.w + (fx + 3.0f) * v4.w;
#pragma unroll
    for (int h = 0; h < HPB; ++h) {
      c[h] += (fmaf(yy[h], u4.x, yx[h] * v4.x) > k0) ? 1 : 0;
      c[h] += (fmaf(yy[h], u4.y, yx[h] * v4.y) > k1) ? 1 : 0;
      c[h] += (fmaf(yy[h], u4.z, yx[h] * v4.z) > k2) ? 1 : 0;
      c[h] += (fmaf(yy[h], u4.w, yx[h] * v4.w) > k3) ? 1 : 0;
    }
  }
  {  // tail: remaining 1024 pixels as float2 (8192 + 2t, coalesced, in-row)
    const int p = 4 * THREADS * 4 + t * 2;
    const float2 u2 = *(const float2*)(uvb + p);
    const float2 v2 = *(const float2*)(uvb + NP + p);
    const int yi = p / Ww;
    const float fy = (float)yi;
    const float fx = (float)(p - yi * Ww);
    const float k0 = fy * u2.x + fx * v2.x;
    const float k1 = fy * u2.y + (fx + 1.0f) * v2.y;
#pragma unroll
    for (int h = 0; h < HPB; ++h) {
      c[h] += (fmaf(yy[h], u2.x, yx[h] * v2.x) > k0) ? 1 : 0;
      c[h] += (fmaf(yy[h], u2.y, yx[h] * v2.y) > k1) ? 1 : 0;
    }
  }
  waveSum2I(c[0], c[1]);
  waveSum2I(c[2], c[3]);
  if (lane == 0) {
#pragma unroll
    for (int h = 0; h < HPB; ++h) sC[wv][h] = c[h];
  }
  __syncthreads();

  // ---- tail: fold 4 hyps -> 3 partials, plain store to own slot ----
  if (t == 0) {
    double wsum = 0.0, ny = 0.0, nx = 0.0;
#pragma unroll
    for (int h = 0; h < HPB; ++h) {
      const int hh = hb + h;
      int cnt = 0;
#pragma unroll
      for (int w8 = 0; w8 < 8; ++w8) cnt += sC[w8][h];
      if (!sNan[hh]) {                   // guard: NaN*0 would poison the sum
        double w = (double)cnt * (double)sWm[hh];
        wsum += w;
        ny += sPy[hh] * w;
        nx += sPx[hh] * w;
      }
    }
    double* slot = partials + (size_t)b * 3 * GPB;
    slot[0 * GPB + g] = wsum;
    slot[1 * GPB + g] = ny;
    slot[2 * GPB + g] = nx;
  }
}

// Kernel 2: 16 blocks x 192 threads (3 waves: w, ny, nx). Deterministic
// fixed-order reduce of the 32 slots; divide once; write out[, ::-1].
__global__ __launch_bounds__(192)
void final_kernel(const double* __restrict__ partials,
                  float* __restrict__ out) {
  __shared__ double sD[3];
  const int t = threadIdx.x;
  const int lane = t & 63;
  const int wv = t >> 6;
  const int b = blockIdx.x;

  double val = (lane < GPB)
                   ? partials[((size_t)b * 3 + wv) * GPB + lane]
                   : 0.0;
  val = waveSumD(val);
  if (lane == 0) sD[wv] = val;
  __syncthreads();
  if (t == 0) {
    double wsum = sD[0];
    out[b * 2 + 0] = (float)(sD[2] / wsum);   // weighted_mean[:, ::-1]
    out[b * 2 + 1] = (float)(sD[1] / wsum);
  }
}

}  // namespace

extern "C" void kernel_launch(void* const* d_in, const int* in_sizes, int n_in,
                              void* d_out, int out_size, void* d_ws, size_t ws_size,
                              hipStream_t stream) {
  const float* uv = (const float*)d_in[0];   // (16,2,96,96) f32
  // d_in[1] = mask, unused (all ones; never read by the reference math)
  const int* pair = (const int*)d_in[2];     // (16,128,2) i32
  float* out = (float*)d_out;                // (16,2) f32

  double* partials = (double*)d_ws;          // 16*3*32*8 = 12288 B

  vote_kernel<<<BATCH * GPB, THREADS, 0, stream>>>(uv, pair, partials);
  final_kernel<<<BATCH, 192, 0, stream>>>(partials, out);
}